// Round 13
// baseline (180.480 us; speedup 1.0000x reference)
//
#include <hip/hip_runtime.h>

#define KP 2048
#define DD 1024
#define DF 128
#define NH 16
#define DKK 64
#define NSS 18
#define NCC 19
#define NCH 8
#define CHUNK 256
#define SPLK 8

typedef __attribute__((ext_vector_type(8))) short short8;
typedef __attribute__((ext_vector_type(4))) short short4_t;
typedef __attribute__((ext_vector_type(4))) float f32x4;

__device__ __forceinline__ short f2bf(float x){
    unsigned u = __float_as_uint(x);
    u += 0x7fffu + ((u >> 16) & 1u);   // round-to-nearest-even
    return (short)(u >> 16);
}

__device__ __forceinline__ void gl2lds16(const void* g, void* l){
    __builtin_amdgcn_global_load_lds((const __attribute__((address_space(1))) void*)g,
                                     (__attribute__((address_space(3))) void*)l, 16, 0, 0);
}

// ---------------- dispatch 1: prep (blocks 0..7) + weight prep (blocks 8..199) ----------------
__global__ __launch_bounds__(256) void prep_convw_kernel(const float* __restrict__ size_scores,
        const float* __restrict__ srn, const float* __restrict__ sem,
        const float* __restrict__ mean,
        const float* __restrict__ w_rank, const float* __restrict__ w_roi,
        const float* __restrict__ Wq, const float* __restrict__ Wk,
        const float* __restrict__ Wv, const float* __restrict__ w_logit,
        float* __restrict__ box, int* __restrict__ label,
        double* __restrict__ probd, double* __restrict__ keyd,
        short* __restrict__ wcat, short* __restrict__ qkT, short* __restrict__ uT){
    int bid = blockIdx.x, t = threadIdx.x;
    if (bid < 8){
        int k = bid * 256 + t;
        const float* ss = size_scores + k * NSS;
        int psc = 0; float bs = ss[0];
        for (int s = 1; s < NSS; s++){ float v = ss[s]; if (v > bs){ bs = v; psc = s; } }
        for (int c = 0; c < 3; c++){
            float m = mean[psc * 3 + c];
            float r = srn[k * (NSS * 3) + psc * 3 + c];
            box[k * 3 + c] = m + r * m;
        }
        const float* cs = sem + k * NCC;
        double mx = (double)cs[0]; int lab = 0;
        for (int c = 1; c < NCC; c++){ double v = (double)cs[c]; if (v > mx){ mx = v; lab = c; } }
        double sum = 0.0;
        for (int c = 0; c < NCC; c++) sum += exp((double)cs[c] - mx);
        probd[k] = 1.0 / sum;
        label[k] = lab;
        keyd[k]  = (lab > 0) ? (1.0 / sum) : -1.0;
        return;
    }
    int b = bid - 8;
    if (b >= 128){   // u[h][f] = sum_e Wv[h][f][e] * wl[h*64+e]
        int i = b - 128;
        int h = i >> 2;
        int f = ((i & 3) << 8) + t;
        const float* wv = Wv + (size_t)h * DD * DKK + (size_t)f * DKK;
        const float* wlh = w_logit + h * DKK;
        float s = 0.f;
        #pragma unroll
        for (int e = 0; e < DKK; e++) s += wv[e] * wlh[e];
        uT[h * DD + f] = f2bf(s);
        return;
    }
    __shared__ float tile[64][65];
    const float* src; short* dst; int sstride, dstride, r0, c0, doff;
    float scale = 1.0f;
    if (b < 32){        src = w_rank; dst = wcat; sstride = DF; dstride = 2048;
                        r0 = (b >> 1) * 64; c0 = (b & 1) * 64; doff = 0; }
    else if (b < 64){   int i = b - 32; src = w_roi; dst = wcat; sstride = DF; dstride = 2048;
                        r0 = (i >> 1) * 64; c0 = (i & 1) * 64; doff = 1024; }
    else if (b < 96){   int i = b - 64; int h = i >> 1;
                        src = Wq + (size_t)h * DF * DKK; dst = qkT + (size_t)h * DKK * DF;
                        sstride = DKK; dstride = DF; r0 = (i & 1) * 64; c0 = 0; doff = 0;
                        scale = 0.18033688011112042f; }  // (1/sqrt(64)) * log2(e): exp(s)=exp2(s')
    else {              int i = b - 96; int h = i >> 1;
                        src = Wk + (size_t)h * DF * DKK; dst = qkT + (size_t)(1024 + h * DKK) * DF;
                        sstride = DKK; dstride = DF; r0 = (i & 1) * 64; c0 = 0; doff = 0; }
    int tx = t & 63, ty = t >> 6;
    #pragma unroll
    for (int pp = 0; pp < 16; pp++){
        int r = pp * 4 + ty;
        tile[r][tx] = src[(size_t)(r0 + r) * sstride + c0 + tx];
    }
    __syncthreads();
    #pragma unroll
    for (int pp = 0; pp < 16; pp++){
        int r = pp * 4 + ty;
        dst[(size_t)(c0 + r) * dstride + doff + r0 + tx] = f2bf(tile[tx][r] * scale);
    }
}

// ---------------- dispatch 2: rank + af fill + dotl + outputs 1,2 ----------------
__global__ __launch_bounds__(256) void rank_af_kernel(const double* __restrict__ keyd,
        const int* __restrict__ label, const double* __restrict__ probd,
        const float* __restrict__ box, const float* __restrict__ app,
        const float* __restrict__ w_logit,
        float* __restrict__ sprob, float* __restrict__ dotl,
        short* __restrict__ af, float* __restrict__ out){
    int i = blockIdx.x, t = threadIdx.x;
    __shared__ int redi[4];
    __shared__ float redf[4];
    __shared__ int rks;
    double ki = keyd[i];
    const double2* k2 = (const double2*)keyd;
    int r = 0;
    #pragma unroll
    for (int pp = 0; pp < KP / 2 / 256; pp++){
        int idx2 = pp * 256 + t;
        double2 kj = k2[idx2];
        int j0 = idx2 * 2;
        r += (int)(kj.x > ki) + (int)((kj.x == ki) & (j0 < i));
        r += (int)(kj.y > ki) + (int)((kj.y == ki) & (j0 + 1 < i));
    }
    #pragma unroll
    for (int off = 32; off > 0; off >>= 1) r += __shfl_down(r, off);
    if ((t & 63) == 0) redi[t >> 6] = r;
    __syncthreads();
    if (t == 0){
        int rk = redi[0] + redi[1] + redi[2] + redi[3];
        rks = rk;
        sprob[rk] = (label[i] > 0) ? (float)probd[i] : 0.f;
        out[KP + rk] = (float)(label[i] - 1);
        out[2 * KP + 3 * rk + 0] = box[i * 3 + 0];
        out[2 * KP + 3 * rk + 1] = box[i * 3 + 1];
        out[2 * KP + 3 * rk + 2] = box[i * 3 + 2];
    }
    __syncthreads();
    int pos = rks;
    // gather + logit-dot (sorted features -> af cols 1024:2048)
    float4 v = ((const float4*)(app + (size_t)i * DD))[t];
    float4 wv = ((const float4*)w_logit)[t];
    short4_t gg = { f2bf(v.x), f2bf(v.y), f2bf(v.z), f2bf(v.w) };
    *(short4_t*)(af + (size_t)pos * 2048 + 1024 + t * 4) = gg;
    float partial = v.x * wv.x + v.y * wv.y + v.z * wv.z + v.w * wv.w;
    #pragma unroll
    for (int off = 32; off > 0; off >>= 1) partial += __shfl_down(partial, off);
    if ((t & 63) == 0) redf[t >> 6] = partial;
    // rank (positional) embedding -> af cols 0:1024
    short4_t e;
    #pragma unroll
    for (int ii = 0; ii < 4; ii++){
        int j = t * 4 + ii, jj = j & 511;
        float inv = exp2f(-(float)jj * 0.0194644224310197f);  // log2(1000)/512
        float arg = (float)pos * inv;
        e[ii] = f2bf((j < 512) ? __sinf(arg) : __cosf(arg));
    }
    *(short4_t*)(af + (size_t)pos * 2048 + t * 4) = e;
    __syncthreads();
    if (t == 0) dotl[pos] = redf[0] + redf[1] + redf[2] + redf[3];
}

// ---------------- LDS-staged bf16 GEMM: 64x64 tile, BK=64, optional split-K slabs ----------------
__global__ __launch_bounds__(256) void gemm_lds(const short* __restrict__ A,
                                                const short* __restrict__ BT,
                                                void* __restrict__ C,
                                                int lda, int ldb, int N,
                                                int klen, size_t slabstride, int mode){
    int w = threadIdx.x >> 6, lane = threadIdx.x & 63;
    int quad = lane >> 4, l16 = lane & 15;
    int m0 = blockIdx.x * 64, n0 = blockIdx.y * 64;
    int kb = blockIdx.z * klen;

    __shared__ __align__(16) short alds[64 * 64];
    __shared__ __align__(16) short blds[64 * 64];

    int p0 = w * 64 + lane;
    int r0 = p0 >> 3, q0 = ((p0 & 7) ^ (r0 & 7)) * 8;
    int p1 = p0 + 256;
    int r1 = p1 >> 3, q1 = ((p1 & 7) ^ (r1 & 7)) * 8;
    short* adst0 = alds + w * 512;
    short* adst1 = alds + 2048 + w * 512;
    short* bdst0 = blds + w * 512;
    short* bdst1 = blds + 2048 + w * 512;
    const short* asrc0 = A + (size_t)(m0 + r0) * lda + kb + q0;
    const short* asrc1 = A + (size_t)(m0 + r1) * lda + kb + q1;
    const short* bsrc0 = BT + (size_t)(n0 + r0) * ldb + kb + q0;
    const short* bsrc1 = BT + (size_t)(n0 + r1) * ldb + kb + q1;

    f32x4 acc[4];
    for (int c = 0; c < 4; c++) acc[c] = (f32x4){0.f, 0.f, 0.f, 0.f};

    for (int kt = 0; kt < klen; kt += 64){
        __syncthreads();
        gl2lds16(asrc0 + kt, adst0);
        gl2lds16(asrc1 + kt, adst1);
        gl2lds16(bsrc0 + kt, bdst0);
        gl2lds16(bsrc1 + kt, bdst1);
        __syncthreads();
        int arow = w * 16 + l16;
        #pragma unroll
        for (int s = 0; s < 2; s++){
            short8 a = *(const short8*)(alds + arow * 64 + (((s * 4 + quad) ^ (l16 & 7)) * 8));
            #pragma unroll
            for (int c = 0; c < 4; c++){
                int brow = c * 16 + l16;
                short8 b = *(const short8*)(blds + brow * 64 + (((s * 4 + quad) ^ (l16 & 7)) * 8));
                acc[c] = __builtin_amdgcn_mfma_f32_16x16x32_bf16(a, b, acc[c], 0, 0, 0);
            }
        }
    }
    int mrow = m0 + w * 16 + quad * 4;
    #pragma unroll
    for (int c = 0; c < 4; c++){
        #pragma unroll
        for (int r = 0; r < 4; r++){
            size_t idx = (size_t)(mrow + r) * N + n0 + c * 16 + l16;
            if (mode == 2) ((short*)C)[idx] = f2bf(acc[c][r]);
            else ((float*)C + (size_t)blockIdx.z * slabstride)[idx] = acc[c][r];
        }
    }
}

// ---------------- dispatch 4: combine e slabs (+biases -> bf16) + vw = sf @ u ----------------
__global__ __launch_bounds__(256) void comb_vw_kernel(const float* __restrict__ es,
        const float* __restrict__ b_rank, const float* __restrict__ b_roi,
        const short* __restrict__ af, const short* __restrict__ uT,
        short* __restrict__ e_bf, float* __restrict__ vwT){
    int bid = blockIdx.x, t = threadIdx.x;
    if (bid < 256){
        int base = (bid * 256 + t) * 4;
        int n = base & (DF - 1);
        float4 s = *(const float4*)(es + base);
        #pragma unroll
        for (int c = 1; c < SPLK; c++){
            float4 tt = *(const float4*)(es + (size_t)c * KP * DF + base);
            s.x += tt.x; s.y += tt.y; s.z += tt.z; s.w += tt.w;
        }
        float4 br = *(const float4*)(b_rank + n);
        float4 bo = *(const float4*)(b_roi + n);
        short4_t o = { f2bf(s.x + br.x + bo.x), f2bf(s.y + br.y + bo.y),
                       f2bf(s.z + br.z + bo.z), f2bf(s.w + br.w + bo.w) };
        *(short4_t*)(e_bf + base) = o;
    } else {
        int vb = bid - 256;
        int w = t >> 6, lane = t & 63, quad = lane >> 4, l16 = lane & 15;
        int m0 = vb * 64 + w * 16;
        f32x4 acc = (f32x4){0.f, 0.f, 0.f, 0.f};
        const short* arow = af + (size_t)(m0 + l16) * 2048 + 1024 + quad * 8;
        const short* brow = uT + (size_t)l16 * DD + quad * 8;
        for (int k0 = 0; k0 < DD; k0 += 32){
            short8 a = *(const short8*)(arow + k0);
            short8 b = *(const short8*)(brow + k0);
            acc = __builtin_amdgcn_mfma_f32_16x16x32_bf16(a, b, acc, 0, 0, 0);
        }
        #pragma unroll
        for (int r = 0; r < 4; r++)
            vwT[(size_t)l16 * KP + m0 + quad * 4 + r] = acc[r];
    }
}

// ---------------- dispatch 6: attention (QK^T, exp2, two weighted row-sums) ----------------
// grid (KP/256, NH, NCH=8) = 1024 blocks; 256 q-rows/block: each staged 64x64 K-tile
// feeds 4 tt-groups (2x compute per barrier, half the staging iterations of R12).
__global__ __launch_bounds__(256, 4) void attn_kernel(const short* __restrict__ qk,
        const float* __restrict__ vwT,
        float* __restrict__ pl, float* __restrict__ pwl){
    int qt = blockIdx.x, h = blockIdx.y, ch = blockIdx.z;
    int t = threadIdx.x;
    int w = t >> 6, lane = t & 63, quad = lane >> 4, l16 = lane & 15;
    int qb = qt * 256;

    __shared__ __align__(16) short klds[64 * 64];

    short8 aq[4][2];
    #pragma unroll
    for (int tt = 0; tt < 4; tt++){
        const short* qrow = qk + (size_t)(qb + tt * 64 + w * 16 + l16) * 2048 + h * DKK;
        aq[tt][0] = *(const short8*)(qrow + quad * 8);
        aq[tt][1] = *(const short8*)(qrow + 32 + quad * 8);
    }
    float lpart[4][4], wpart[4][4];
    #pragma unroll
    for (int tt = 0; tt < 4; tt++)
        #pragma unroll
        for (int rr = 0; rr < 4; rr++){ lpart[tt][rr] = 0.f; wpart[tt][rr] = 0.f; }

    int seg0 = w * 128 + lane;
    int row0 = seg0 >> 3, c80 = (seg0 & 7) ^ (row0 & 7);
    int seg1 = seg0 + 64;
    int row1 = seg1 >> 3, c81 = (seg1 & 7) ^ (row1 & 7);
    short* kl0 = klds + (size_t)(w * 128) * 8;
    short* kl1 = klds + (size_t)(w * 128 + 64) * 8;

    for (int m0 = ch * CHUNK; m0 < (ch + 1) * CHUNK; m0 += 64){
        __syncthreads();
        gl2lds16(qk + (size_t)(m0 + row0) * 2048 + 1024 + h * DKK + c80 * 8, kl0);
        gl2lds16(qk + (size_t)(m0 + row1) * 2048 + 1024 + h * DKK + c81 * 8, kl1);
        float vwv[4];
        #pragma unroll
        for (int c = 0; c < 4; c++)
            vwv[c] = vwT[(size_t)h * KP + m0 + c * 16 + l16];
        __syncthreads();

        #pragma unroll
        for (int tt = 0; tt < 4; tt++){
            #pragma unroll
            for (int c = 0; c < 4; c++){
                int r = c * 16 + l16, sw = r & 7;
                short8 b0 = *(const short8*)(klds + r * 64 + (quad ^ sw) * 8);
                short8 b1 = *(const short8*)(klds + r * 64 + ((quad + 4) ^ sw) * 8);
                f32x4 acc = (f32x4){0.f, 0.f, 0.f, 0.f};
                acc = __builtin_amdgcn_mfma_f32_16x16x32_bf16(aq[tt][0], b0, acc, 0, 0, 0);
                acc = __builtin_amdgcn_mfma_f32_16x16x32_bf16(aq[tt][1], b1, acc, 0, 0, 0);
                #pragma unroll
                for (int rr = 0; rr < 4; rr++){
                    float e = exp2f(acc[rr]);   // scores pre-scaled by log2(e): one v_exp_f32
                    lpart[tt][rr] += e;
                    wpart[tt][rr] += e * vwv[c];
                }
            }
        }
    }

    #pragma unroll
    for (int tt = 0; tt < 4; tt++){
        #pragma unroll
        for (int rr = 0; rr < 4; rr++){
            float v = lpart[tt][rr], x = wpart[tt][rr];
            v += __shfl_xor(v, 1); x += __shfl_xor(x, 1);
            v += __shfl_xor(v, 2); x += __shfl_xor(x, 2);
            v += __shfl_xor(v, 4); x += __shfl_xor(x, 4);
            v += __shfl_xor(v, 8); x += __shfl_xor(x, 8);
            lpart[tt][rr] = v; wpart[tt][rr] = x;
        }
        if (l16 == 0){
            int qr0 = qb + tt * 64 + w * 16;
            #pragma unroll
            for (int rr = 0; rr < 4; rr++){
                size_t idx = ((size_t)ch * NH + h) * KP + qr0 + quad * 4 + rr;
                pl[idx]  = lpart[tt][rr];
                pwl[idx] = wpart[tt][rr];
            }
        }
    }
}

// ---------------- dispatch 7: final logit + score (1 thread per proposal) ----------------
__global__ __launch_bounds__(256) void final_kernel(const float* __restrict__ dotl,
        const float* __restrict__ pl, const float* __restrict__ pwl,
        const float* __restrict__ sprob, const float* __restrict__ b_logit,
        float* __restrict__ out){
    int pos = blockIdx.x * 256 + threadIdx.x;
    float logit = dotl[pos] + b_logit[0];
    #pragma unroll
    for (int h = 0; h < NH; h++){
        float l = 0.f, x = 0.f;
        #pragma unroll
        for (int c = 0; c < NCH; c++){
            size_t idx = ((size_t)c * NH + h) * KP + pos;
            l += pl[idx]; x += pwl[idx];
        }
        logit += x / l;
    }
    float s1 = 1.f / (1.f + __expf(-logit));
    out[pos] = s1 * sprob[pos];
}

extern "C" void kernel_launch(void* const* d_in, const int* in_sizes, int n_in,
                              void* d_out, int out_size, void* d_ws, size_t ws_size,
                              hipStream_t stream){
    (void)in_sizes; (void)n_in; (void)out_size; (void)ws_size;
    const float* size_scores = (const float*)d_in[0];
    const float* srn     = (const float*)d_in[1];
    const float* sem     = (const float*)d_in[2];
    const float* app     = (const float*)d_in[3];
    const float* mean    = (const float*)d_in[4];
    const float* w_rank  = (const float*)d_in[5];
    const float* b_rank  = (const float*)d_in[6];
    const float* w_roi   = (const float*)d_in[7];
    const float* b_roi   = (const float*)d_in[8];
    const float* Wq      = (const float*)d_in[9];
    const float* Wk      = (const float*)d_in[10];
    const float* Wv      = (const float*)d_in[11];
    const float* w_logit = (const float*)d_in[12];
    const float* b_logit = (const float*)d_in[13];
    float* out = (float*)d_out;

    char* ws = (char*)d_ws;
    size_t off = 0;
    auto alloc = [&](size_t n) -> char* {
        char* pp = ws + off;
        off = (off + n + 255) & ~(size_t)255;
        return pp;
    };
    float*  box   = (float*)  alloc((size_t)KP * 3 * 4);
    int*    label = (int*)    alloc((size_t)KP * 4);
    double* probd = (double*) alloc((size_t)KP * 8);
    double* keyd  = (double*) alloc((size_t)KP * 8);
    float*  sprob = (float*)  alloc((size_t)KP * 4);
    float*  dotl  = (float*)  alloc((size_t)KP * 4);
    short*  wcat  = (short*)  alloc((size_t)DF * 2048 * 2);
    short*  qkT   = (short*)  alloc((size_t)2048 * DF * 2);
    short*  uT    = (short*)  alloc((size_t)NH * DD * 2);
    short*  e_bf  = (short*)  alloc((size_t)KP * DF * 2);
    short*  qk_bf = (short*)  alloc((size_t)KP * 2048 * 2);
    float*  vwT   = (float*)  alloc((size_t)NH * KP * 4);
    float*  pl    = (float*)  alloc((size_t)NCH * NH * KP * 4);
    float*  pwl   = (float*)  alloc((size_t)NCH * NH * KP * 4);
    short*  af    = (short*)  alloc((size_t)KP * 2048 * 2);
    float*  es    = (float*)  alloc((size_t)SPLK * KP * DF * 4);

    prep_convw_kernel<<<200, 256, 0, stream>>>(size_scores, srn, sem, mean,
        w_rank, w_roi, Wq, Wk, Wv, w_logit, box, label, probd, keyd, wcat, qkT, uT);
    rank_af_kernel<<<KP, 256, 0, stream>>>(keyd, label, probd, box, app, w_logit,
        sprob, dotl, af, out);
    gemm_lds<<<dim3(32, 2, SPLK), 256, 0, stream>>>(af, wcat, es, 2048, 2048, DF,
        2048 / SPLK, (size_t)KP * DF, 0);
    comb_vw_kernel<<<288, 256, 0, stream>>>(es, b_rank, b_roi, af, uT, e_bf, vwT);
    gemm_lds<<<dim3(32, 32, 1), 256, 0, stream>>>(e_bf, qkT, qk_bf, DF, DF, 2048, DF, 0, 2);
    attn_kernel<<<dim3(KP / 256, NH, NCH), 256, 0, stream>>>(qk_bf, vwT, pl, pwl);
    final_kernel<<<KP / 256, 256, 0, stream>>>(dotl, pl, pwl, sprob, b_logit, out);
}

// Round 14
// 144.428 us; speedup vs baseline: 1.2496x; 1.2496x over previous
//
#include <hip/hip_runtime.h>

#define KP 2048
#define DD 1024
#define DF 128
#define NH 16
#define DKK 64
#define NSS 18
#define NCC 19
#define NCH 4
#define CHUNK 512
#define SPLK 8

typedef __attribute__((ext_vector_type(8))) short short8;
typedef __attribute__((ext_vector_type(4))) short short4_t;
typedef __attribute__((ext_vector_type(4))) float f32x4;

__device__ __forceinline__ short f2bf(float x){
    unsigned u = __float_as_uint(x);
    u += 0x7fffu + ((u >> 16) & 1u);   // round-to-nearest-even
    return (short)(u >> 16);
}

__device__ __forceinline__ void gl2lds16(const void* g, void* l){
    __builtin_amdgcn_global_load_lds((const __attribute__((address_space(1))) void*)g,
                                     (__attribute__((address_space(3))) void*)l, 16, 0, 0);
}

// ---------------- dispatch 1: prep (blocks 0..7) + weight prep (blocks 8..199) ----------------
__global__ __launch_bounds__(256) void prep_convw_kernel(const float* __restrict__ size_scores,
        const float* __restrict__ srn, const float* __restrict__ sem,
        const float* __restrict__ mean,
        const float* __restrict__ w_rank, const float* __restrict__ w_roi,
        const float* __restrict__ Wq, const float* __restrict__ Wk,
        const float* __restrict__ Wv, const float* __restrict__ w_logit,
        float* __restrict__ box, int* __restrict__ label,
        double* __restrict__ probd, double* __restrict__ keyd,
        short* __restrict__ wcat, short* __restrict__ qkT, short* __restrict__ uT){
    int bid = blockIdx.x, t = threadIdx.x;
    if (bid < 8){
        int k = bid * 256 + t;
        const float* ss = size_scores + k * NSS;
        int psc = 0; float bs = ss[0];
        for (int s = 1; s < NSS; s++){ float v = ss[s]; if (v > bs){ bs = v; psc = s; } }
        for (int c = 0; c < 3; c++){
            float m = mean[psc * 3 + c];
            float r = srn[k * (NSS * 3) + psc * 3 + c];
            box[k * 3 + c] = m + r * m;
        }
        const float* cs = sem + k * NCC;
        double mx = (double)cs[0]; int lab = 0;
        for (int c = 1; c < NCC; c++){ double v = (double)cs[c]; if (v > mx){ mx = v; lab = c; } }
        double sum = 0.0;
        for (int c = 0; c < NCC; c++) sum += exp((double)cs[c] - mx);
        probd[k] = 1.0 / sum;
        label[k] = lab;
        keyd[k]  = (lab > 0) ? (1.0 / sum) : -1.0;
        return;
    }
    int b = bid - 8;
    if (b >= 128){   // u[h][f] = sum_e Wv[h][f][e] * wl[h*64+e]
        int i = b - 128;
        int h = i >> 2;
        int f = ((i & 3) << 8) + t;
        const float* wv = Wv + (size_t)h * DD * DKK + (size_t)f * DKK;
        const float* wlh = w_logit + h * DKK;
        float s = 0.f;
        #pragma unroll
        for (int e = 0; e < DKK; e++) s += wv[e] * wlh[e];
        uT[h * DD + f] = f2bf(s);
        return;
    }
    __shared__ float tile[64][65];
    const float* src; short* dst; int sstride, dstride, r0, c0, doff;
    float scale = 1.0f;
    if (b < 32){        src = w_rank; dst = wcat; sstride = DF; dstride = 2048;
                        r0 = (b >> 1) * 64; c0 = (b & 1) * 64; doff = 0; }
    else if (b < 64){   int i = b - 32; src = w_roi; dst = wcat; sstride = DF; dstride = 2048;
                        r0 = (i >> 1) * 64; c0 = (i & 1) * 64; doff = 1024; }
    else if (b < 96){   int i = b - 64; int h = i >> 1;
                        src = Wq + (size_t)h * DF * DKK; dst = qkT + (size_t)h * DKK * DF;
                        sstride = DKK; dstride = DF; r0 = (i & 1) * 64; c0 = 0; doff = 0;
                        scale = 0.18033688011112042f; }  // (1/sqrt(64)) * log2(e): exp(s)=exp2(s')
    else {              int i = b - 96; int h = i >> 1;
                        src = Wk + (size_t)h * DF * DKK; dst = qkT + (size_t)(1024 + h * DKK) * DF;
                        sstride = DKK; dstride = DF; r0 = (i & 1) * 64; c0 = 0; doff = 0; }
    int tx = t & 63, ty = t >> 6;
    #pragma unroll
    for (int pp = 0; pp < 16; pp++){
        int r = pp * 4 + ty;
        tile[r][tx] = src[(size_t)(r0 + r) * sstride + c0 + tx];
    }
    __syncthreads();
    #pragma unroll
    for (int pp = 0; pp < 16; pp++){
        int r = pp * 4 + ty;
        dst[(size_t)(c0 + r) * dstride + doff + r0 + tx] = f2bf(tile[tx][r] * scale);
    }
}

// ---------------- dispatch 2: rank + af fill + dotl + outputs 1,2 ----------------
__global__ __launch_bounds__(256) void rank_af_kernel(const double* __restrict__ keyd,
        const int* __restrict__ label, const double* __restrict__ probd,
        const float* __restrict__ box, const float* __restrict__ app,
        const float* __restrict__ w_logit,
        float* __restrict__ sprob, float* __restrict__ dotl,
        short* __restrict__ af, float* __restrict__ out){
    int i = blockIdx.x, t = threadIdx.x;
    __shared__ int redi[4];
    __shared__ float redf[4];
    __shared__ int rks;
    double ki = keyd[i];
    const double2* k2 = (const double2*)keyd;
    int r = 0;
    #pragma unroll
    for (int pp = 0; pp < KP / 2 / 256; pp++){
        int idx2 = pp * 256 + t;
        double2 kj = k2[idx2];
        int j0 = idx2 * 2;
        r += (int)(kj.x > ki) + (int)((kj.x == ki) & (j0 < i));
        r += (int)(kj.y > ki) + (int)((kj.y == ki) & (j0 + 1 < i));
    }
    #pragma unroll
    for (int off = 32; off > 0; off >>= 1) r += __shfl_down(r, off);
    if ((t & 63) == 0) redi[t >> 6] = r;
    __syncthreads();
    if (t == 0){
        int rk = redi[0] + redi[1] + redi[2] + redi[3];
        rks = rk;
        sprob[rk] = (label[i] > 0) ? (float)probd[i] : 0.f;
        out[KP + rk] = (float)(label[i] - 1);
        out[2 * KP + 3 * rk + 0] = box[i * 3 + 0];
        out[2 * KP + 3 * rk + 1] = box[i * 3 + 1];
        out[2 * KP + 3 * rk + 2] = box[i * 3 + 2];
    }
    __syncthreads();
    int pos = rks;
    // gather + logit-dot (sorted features -> af cols 1024:2048)
    float4 v = ((const float4*)(app + (size_t)i * DD))[t];
    float4 wv = ((const float4*)w_logit)[t];
    short4_t gg = { f2bf(v.x), f2bf(v.y), f2bf(v.z), f2bf(v.w) };
    *(short4_t*)(af + (size_t)pos * 2048 + 1024 + t * 4) = gg;
    float partial = v.x * wv.x + v.y * wv.y + v.z * wv.z + v.w * wv.w;
    #pragma unroll
    for (int off = 32; off > 0; off >>= 1) partial += __shfl_down(partial, off);
    if ((t & 63) == 0) redf[t >> 6] = partial;
    // rank (positional) embedding -> af cols 0:1024
    short4_t e;
    #pragma unroll
    for (int ii = 0; ii < 4; ii++){
        int j = t * 4 + ii, jj = j & 511;
        float inv = exp2f(-(float)jj * 0.0194644224310197f);  // log2(1000)/512
        float arg = (float)pos * inv;
        e[ii] = f2bf((j < 512) ? __sinf(arg) : __cosf(arg));
    }
    *(short4_t*)(af + (size_t)pos * 2048 + t * 4) = e;
    __syncthreads();
    if (t == 0) dotl[pos] = redf[0] + redf[1] + redf[2] + redf[3];
}

// ---------------- LDS-staged bf16 GEMM: 64x64 tile, BK=64, optional split-K slabs ----------------
__global__ __launch_bounds__(256) void gemm_lds(const short* __restrict__ A,
                                                const short* __restrict__ BT,
                                                void* __restrict__ C,
                                                int lda, int ldb, int N,
                                                int klen, size_t slabstride, int mode){
    int w = threadIdx.x >> 6, lane = threadIdx.x & 63;
    int quad = lane >> 4, l16 = lane & 15;
    int m0 = blockIdx.x * 64, n0 = blockIdx.y * 64;
    int kb = blockIdx.z * klen;

    __shared__ __align__(16) short alds[64 * 64];
    __shared__ __align__(16) short blds[64 * 64];

    int p0 = w * 64 + lane;
    int r0 = p0 >> 3, q0 = ((p0 & 7) ^ (r0 & 7)) * 8;
    int p1 = p0 + 256;
    int r1 = p1 >> 3, q1 = ((p1 & 7) ^ (r1 & 7)) * 8;
    short* adst0 = alds + w * 512;
    short* adst1 = alds + 2048 + w * 512;
    short* bdst0 = blds + w * 512;
    short* bdst1 = blds + 2048 + w * 512;
    const short* asrc0 = A + (size_t)(m0 + r0) * lda + kb + q0;
    const short* asrc1 = A + (size_t)(m0 + r1) * lda + kb + q1;
    const short* bsrc0 = BT + (size_t)(n0 + r0) * ldb + kb + q0;
    const short* bsrc1 = BT + (size_t)(n0 + r1) * ldb + kb + q1;

    f32x4 acc[4];
    for (int c = 0; c < 4; c++) acc[c] = (f32x4){0.f, 0.f, 0.f, 0.f};

    for (int kt = 0; kt < klen; kt += 64){
        __syncthreads();
        gl2lds16(asrc0 + kt, adst0);
        gl2lds16(asrc1 + kt, adst1);
        gl2lds16(bsrc0 + kt, bdst0);
        gl2lds16(bsrc1 + kt, bdst1);
        __syncthreads();
        int arow = w * 16 + l16;
        #pragma unroll
        for (int s = 0; s < 2; s++){
            short8 a = *(const short8*)(alds + arow * 64 + (((s * 4 + quad) ^ (l16 & 7)) * 8));
            #pragma unroll
            for (int c = 0; c < 4; c++){
                int brow = c * 16 + l16;
                short8 b = *(const short8*)(blds + brow * 64 + (((s * 4 + quad) ^ (l16 & 7)) * 8));
                acc[c] = __builtin_amdgcn_mfma_f32_16x16x32_bf16(a, b, acc[c], 0, 0, 0);
            }
        }
    }
    int mrow = m0 + w * 16 + quad * 4;
    #pragma unroll
    for (int c = 0; c < 4; c++){
        #pragma unroll
        for (int r = 0; r < 4; r++){
            size_t idx = (size_t)(mrow + r) * N + n0 + c * 16 + l16;
            if (mode == 2) ((short*)C)[idx] = f2bf(acc[c][r]);
            else ((float*)C + (size_t)blockIdx.z * slabstride)[idx] = acc[c][r];
        }
    }
}

// ---------------- dispatch 4: combine e slabs (+biases -> bf16) + vw = sf @ u ----------------
__global__ __launch_bounds__(256) void comb_vw_kernel(const float* __restrict__ es,
        const float* __restrict__ b_rank, const float* __restrict__ b_roi,
        const short* __restrict__ af, const short* __restrict__ uT,
        short* __restrict__ e_bf, float* __restrict__ vwT){
    int bid = blockIdx.x, t = threadIdx.x;
    if (bid < 256){
        int base = (bid * 256 + t) * 4;
        int n = base & (DF - 1);
        float4 s = *(const float4*)(es + base);
        #pragma unroll
        for (int c = 1; c < SPLK; c++){
            float4 tt = *(const float4*)(es + (size_t)c * KP * DF + base);
            s.x += tt.x; s.y += tt.y; s.z += tt.z; s.w += tt.w;
        }
        float4 br = *(const float4*)(b_rank + n);
        float4 bo = *(const float4*)(b_roi + n);
        short4_t o = { f2bf(s.x + br.x + bo.x), f2bf(s.y + br.y + bo.y),
                       f2bf(s.z + br.z + bo.z), f2bf(s.w + br.w + bo.w) };
        *(short4_t*)(e_bf + base) = o;
    } else {
        int vb = bid - 256;
        int w = t >> 6, lane = t & 63, quad = lane >> 4, l16 = lane & 15;
        int m0 = vb * 64 + w * 16;
        f32x4 acc = (f32x4){0.f, 0.f, 0.f, 0.f};
        const short* arow = af + (size_t)(m0 + l16) * 2048 + 1024 + quad * 8;
        const short* brow = uT + (size_t)l16 * DD + quad * 8;
        for (int k0 = 0; k0 < DD; k0 += 32){
            short8 a = *(const short8*)(arow + k0);
            short8 b = *(const short8*)(brow + k0);
            acc = __builtin_amdgcn_mfma_f32_16x16x32_bf16(a, b, acc, 0, 0, 0);
        }
        #pragma unroll
        for (int r = 0; r < 4; r++)
            vwT[(size_t)l16 * KP + m0 + quad * 4 + r] = acc[r];
    }
}

// ---------------- dispatch 6: attention (QK^T, exp2, two weighted row-sums) ----------------
// grid (KP/128, NH, NCH=4) = 1024 blocks; 128 q-rows/block (R12-validated: no spills
// at launch_bounds(256,4)); scores pre-scaled by log2(e) so exp() is one v_exp_f32.
__global__ __launch_bounds__(256, 4) void attn_kernel(const short* __restrict__ qk,
        const float* __restrict__ vwT,
        float* __restrict__ pl, float* __restrict__ pwl){
    int qt = blockIdx.x, h = blockIdx.y, ch = blockIdx.z;
    int t = threadIdx.x;
    int w = t >> 6, lane = t & 63, quad = lane >> 4, l16 = lane & 15;
    int qb = qt * 128;

    __shared__ __align__(16) short klds[64 * 64];

    short8 aq[2][2];
    #pragma unroll
    for (int tt = 0; tt < 2; tt++){
        const short* qrow = qk + (size_t)(qb + tt * 64 + w * 16 + l16) * 2048 + h * DKK;
        aq[tt][0] = *(const short8*)(qrow + quad * 8);
        aq[tt][1] = *(const short8*)(qrow + 32 + quad * 8);
    }
    float lpart[2][4] = {{0.f,0.f,0.f,0.f},{0.f,0.f,0.f,0.f}};
    float wpart[2][4] = {{0.f,0.f,0.f,0.f},{0.f,0.f,0.f,0.f}};

    int seg0 = w * 128 + lane;
    int row0 = seg0 >> 3, c80 = (seg0 & 7) ^ (row0 & 7);
    int seg1 = seg0 + 64;
    int row1 = seg1 >> 3, c81 = (seg1 & 7) ^ (row1 & 7);
    short* kl0 = klds + (size_t)(w * 128) * 8;
    short* kl1 = klds + (size_t)(w * 128 + 64) * 8;

    for (int m0 = ch * CHUNK; m0 < (ch + 1) * CHUNK; m0 += 64){
        __syncthreads();
        gl2lds16(qk + (size_t)(m0 + row0) * 2048 + 1024 + h * DKK + c80 * 8, kl0);
        gl2lds16(qk + (size_t)(m0 + row1) * 2048 + 1024 + h * DKK + c81 * 8, kl1);
        float vwv[4];
        #pragma unroll
        for (int c = 0; c < 4; c++)
            vwv[c] = vwT[(size_t)h * KP + m0 + c * 16 + l16];
        __syncthreads();

        #pragma unroll
        for (int tt = 0; tt < 2; tt++){
            #pragma unroll
            for (int c = 0; c < 4; c++){
                int r = c * 16 + l16, sw = r & 7;
                short8 b0 = *(const short8*)(klds + r * 64 + (quad ^ sw) * 8);
                short8 b1 = *(const short8*)(klds + r * 64 + ((quad + 4) ^ sw) * 8);
                f32x4 acc = (f32x4){0.f, 0.f, 0.f, 0.f};
                acc = __builtin_amdgcn_mfma_f32_16x16x32_bf16(aq[tt][0], b0, acc, 0, 0, 0);
                acc = __builtin_amdgcn_mfma_f32_16x16x32_bf16(aq[tt][1], b1, acc, 0, 0, 0);
                #pragma unroll
                for (int rr = 0; rr < 4; rr++){
                    float e = exp2f(acc[rr]);   // pre-scaled by log2(e): bare v_exp_f32
                    lpart[tt][rr] += e;
                    wpart[tt][rr] += e * vwv[c];
                }
            }
        }
    }

    #pragma unroll
    for (int tt = 0; tt < 2; tt++){
        #pragma unroll
        for (int rr = 0; rr < 4; rr++){
            float v = lpart[tt][rr], x = wpart[tt][rr];
            v += __shfl_xor(v, 1); x += __shfl_xor(x, 1);
            v += __shfl_xor(v, 2); x += __shfl_xor(x, 2);
            v += __shfl_xor(v, 4); x += __shfl_xor(x, 4);
            v += __shfl_xor(v, 8); x += __shfl_xor(x, 8);
            lpart[tt][rr] = v; wpart[tt][rr] = x;
        }
        if (l16 == 0){
            int qr0 = qb + tt * 64 + w * 16;
            #pragma unroll
            for (int rr = 0; rr < 4; rr++){
                size_t idx = ((size_t)ch * NH + h) * KP + qr0 + quad * 4 + rr;
                pl[idx]  = lpart[tt][rr];
                pwl[idx] = wpart[tt][rr];
            }
        }
    }
}

// ---------------- dispatch 7: final logit + score (1 thread per proposal) ----------------
__global__ __launch_bounds__(256) void final_kernel(const float* __restrict__ dotl,
        const float* __restrict__ pl, const float* __restrict__ pwl,
        const float* __restrict__ sprob, const float* __restrict__ b_logit,
        float* __restrict__ out){
    int pos = blockIdx.x * 256 + threadIdx.x;
    float logit = dotl[pos] + b_logit[0];
    #pragma unroll
    for (int h = 0; h < NH; h++){
        float l = 0.f, x = 0.f;
        #pragma unroll
        for (int c = 0; c < NCH; c++){
            size_t idx = ((size_t)c * NH + h) * KP + pos;
            l += pl[idx]; x += pwl[idx];
        }
        logit += x / l;
    }
    float s1 = 1.f / (1.f + __expf(-logit));
    out[pos] = s1 * sprob[pos];
}

extern "C" void kernel_launch(void* const* d_in, const int* in_sizes, int n_in,
                              void* d_out, int out_size, void* d_ws, size_t ws_size,
                              hipStream_t stream){
    (void)in_sizes; (void)n_in; (void)out_size; (void)ws_size;
    const float* size_scores = (const float*)d_in[0];
    const float* srn     = (const float*)d_in[1];
    const float* sem     = (const float*)d_in[2];
    const float* app     = (const float*)d_in[3];
    const float* mean    = (const float*)d_in[4];
    const float* w_rank  = (const float*)d_in[5];
    const float* b_rank  = (const float*)d_in[6];
    const float* w_roi   = (const float*)d_in[7];
    const float* b_roi   = (const float*)d_in[8];
    const float* Wq      = (const float*)d_in[9];
    const float* Wk      = (const float*)d_in[10];
    const float* Wv      = (const float*)d_in[11];
    const float* w_logit = (const float*)d_in[12];
    const float* b_logit = (const float*)d_in[13];
    float* out = (float*)d_out;

    char* ws = (char*)d_ws;
    size_t off = 0;
    auto alloc = [&](size_t n) -> char* {
        char* pp = ws + off;
        off = (off + n + 255) & ~(size_t)255;
        return pp;
    };
    float*  box   = (float*)  alloc((size_t)KP * 3 * 4);
    int*    label = (int*)    alloc((size_t)KP * 4);
    double* probd = (double*) alloc((size_t)KP * 8);
    double* keyd  = (double*) alloc((size_t)KP * 8);
    float*  sprob = (float*)  alloc((size_t)KP * 4);
    float*  dotl  = (float*)  alloc((size_t)KP * 4);
    short*  wcat  = (short*)  alloc((size_t)DF * 2048 * 2);
    short*  qkT   = (short*)  alloc((size_t)2048 * DF * 2);
    short*  uT    = (short*)  alloc((size_t)NH * DD * 2);
    short*  e_bf  = (short*)  alloc((size_t)KP * DF * 2);
    short*  qk_bf = (short*)  alloc((size_t)KP * 2048 * 2);
    float*  vwT   = (float*)  alloc((size_t)NH * KP * 4);
    float*  pl    = (float*)  alloc((size_t)NCH * NH * KP * 4);
    float*  pwl   = (float*)  alloc((size_t)NCH * NH * KP * 4);
    short*  af    = (short*)  alloc((size_t)KP * 2048 * 2);
    float*  es    = (float*)  alloc((size_t)SPLK * KP * DF * 4);

    prep_convw_kernel<<<200, 256, 0, stream>>>(size_scores, srn, sem, mean,
        w_rank, w_roi, Wq, Wk, Wv, w_logit, box, label, probd, keyd, wcat, qkT, uT);
    rank_af_kernel<<<KP, 256, 0, stream>>>(keyd, label, probd, box, app, w_logit,
        sprob, dotl, af, out);
    gemm_lds<<<dim3(32, 2, SPLK), 256, 0, stream>>>(af, wcat, es, 2048, 2048, DF,
        2048 / SPLK, (size_t)KP * DF, 0);
    comb_vw_kernel<<<288, 256, 0, stream>>>(es, b_rank, b_roi, af, uT, e_bf, vwT);
    gemm_lds<<<dim3(32, 32, 1), 256, 0, stream>>>(e_bf, qkT, qk_bf, DF, DF, 2048, DF, 0, 2);
    attn_kernel<<<dim3(KP / 128, NH, NCH), 256, 0, stream>>>(qk_bf, vwT, pl, pwl);
    final_kernel<<<KP / 256, 256, 0, stream>>>(dotl, pl, pwl, sprob, b_logit, out);
}